// Round 13
// baseline (636.022 us; speedup 1.0000x reference)
//
#include <hip/hip_runtime.h>
#include <stdint.h>

#define N_NODES 100000
#define D 256
#define NT 4

typedef float f32x4 __attribute__((ext_vector_type(4)));
typedef __bf16 bf16x8 __attribute__((ext_vector_type(8)));
typedef unsigned int uint32x4 __attribute__((ext_vector_type(4)));
typedef unsigned int uint32x2 __attribute__((ext_vector_type(2)));

__device__ __forceinline__ unsigned short f2bf(float f) {
    unsigned u = __float_as_uint(f);
    u += 0x7FFF + ((u >> 16) & 1);        // round-to-nearest-even
    return (unsigned short)(u >> 16);
}

__device__ __forceinline__ void gload_lds16(const void* g, void* lds) {
    __builtin_amdgcn_global_load_lds(
        (const __attribute__((address_space(1))) unsigned int*)g,
        (__attribute__((address_space(3))) unsigned int*)lds, 16, 0, 0);
}

// ---------------- fused counting: (t,dst) AND (t,src0) cells, both stages ----------------
// counts segments: [dst1 | dst2 | src1 | src2], each NT*N_NODES.

__global__ void k_count_all(const int* __restrict__ idx1, const int* __restrict__ ty1, int E1,
                            const int* __restrict__ idx2, const int* __restrict__ ty2, int E2,
                            int* __restrict__ counts) {
    const int NC = NT * N_NODES;
    int e = blockIdx.x * 256 + threadIdx.x;
    if (e < E1) {
        int t = ty1[e];
        atomicAdd(&counts[t * N_NODES + idx1[(size_t)E1 + e]], 1);
        atomicAdd(&counts[2 * NC + t * N_NODES + idx1[e]], 1);
    }
    if (e < E2) {
        int t = ty2[e];
        atomicAdd(&counts[NC + t * N_NODES + idx2[(size_t)2 * E2 + (size_t)2 * e]], 1);
        atomicAdd(&counts[3 * NC + t * N_NODES + idx2[(size_t)2 * e]], 1);
    }
}

// ---------------- exclusive scan over 4*NT*N_NODES cells (3 kernels) ----------------

__global__ __launch_bounds__(256) void k_scan1(const int* __restrict__ in, int n,
        int* __restrict__ outv, int* __restrict__ bsums) {
    __shared__ int s[256];
    int tid = threadIdx.x;
    int i = blockIdx.x * 1024 + tid * 4;
    int v0 = 0, v1 = 0, v2 = 0, v3 = 0;
    if (i + 3 < n) {
        int4 v = *(const int4*)(in + i);
        v0 = v.x; v1 = v.y; v2 = v.z; v3 = v.w;
    } else {
        if (i     < n) v0 = in[i];
        if (i + 1 < n) v1 = in[i + 1];
        if (i + 2 < n) v2 = in[i + 2];
        if (i + 3 < n) v3 = in[i + 3];
    }
    int tsum = v0 + v1 + v2 + v3;
    s[tid] = tsum; __syncthreads();
    for (int off = 1; off < 256; off <<= 1) {
        int t = (tid >= off) ? s[tid - off] : 0;
        __syncthreads();
        s[tid] += t;
        __syncthreads();
    }
    int excl = s[tid] - tsum;
    if (tid == 255) bsums[blockIdx.x] = s[255];
    int o0 = excl, o1 = o0 + v0, o2 = o1 + v1, o3 = o2 + v2;
    if (i + 3 < n) {
        *(int4*)(outv + i) = make_int4(o0, o1, o2, o3);
    } else {
        if (i     < n) outv[i]     = o0;
        if (i + 1 < n) outv[i + 1] = o1;
        if (i + 2 < n) outv[i + 2] = o2;
        if (i + 3 < n) outv[i + 3] = o3;
    }
}

// capacity 2048 block sums: thread t owns elements 2t, 2t+1
__global__ __launch_bounds__(1024) void k_scan2(int* __restrict__ bsums, int nb) {
    __shared__ int s[1024];
    int t = threadIdx.x;
    int v0 = (2 * t     < nb) ? bsums[2 * t]     : 0;
    int v1 = (2 * t + 1 < nb) ? bsums[2 * t + 1] : 0;
    int tsum = v0 + v1;
    s[t] = tsum; __syncthreads();
    for (int off = 1; off < 1024; off <<= 1) {
        int u = (t >= off) ? s[t - off] : 0;
        __syncthreads();
        s[t] += u;
        __syncthreads();
    }
    int excl = s[t] - tsum;
    if (2 * t     < nb) bsums[2 * t]     = excl;
    if (2 * t + 1 < nb) bsums[2 * t + 1] = excl + v0;
}

__global__ __launch_bounds__(256) void k_scan3(int* __restrict__ cellofs,
        int* __restrict__ cellcur, const int* __restrict__ bsums, int n) {
    int i = blockIdx.x * 1024 + threadIdx.x * 4;
    int add = bsums[blockIdx.x];
    if (i + 3 < n) {
        int4 v = *(int4*)(cellofs + i);
        v.x += add; v.y += add; v.z += add; v.w += add;
        *(int4*)(cellofs + i) = v;
        *(int4*)(cellcur + i) = v;
    } else {
        for (int k = 0; k < 4; ++k)
            if (i + k < n) { int v = cellofs[i + k] + add; cellofs[i + k] = v; cellcur[i + k] = v; }
    }
}

// ---------------- fused placement: dst-rank (epos) + src-sorted bucket ----------------

__global__ void k_place_all(const int* __restrict__ idx1, const int* __restrict__ ty1, int E1,
                            int* __restrict__ epos1, int* __restrict__ bucketS1,
                            const int* __restrict__ idx2, const int* __restrict__ ty2, int E2,
                            int* __restrict__ epos2, int* __restrict__ bucketS2,
                            int* __restrict__ cellcur) {
    const int NC = NT * N_NODES;
    int e = blockIdx.x * 256 + threadIdx.x;
    if (e < E1) {
        int t = ty1[e];
        int dst = idx1[(size_t)E1 + e];
        int src = idx1[e];
        epos1[e] = atomicAdd(&cellcur[t * N_NODES + dst], 1);             // seg0 base 0
        int ps = atomicAdd(&cellcur[2 * NC + t * N_NODES + src], 1) - (E1 + E2);
        bucketS1[ps] = e;
    }
    if (e < E2) {
        int t = ty2[e];
        int dst = idx2[(size_t)2 * E2 + (size_t)2 * e];
        int src = idx2[(size_t)2 * e];
        epos2[e] = atomicAdd(&cellcur[NC + t * N_NODES + dst], 1) - E1;   // seg1 base E1
        int ps = atomicAdd(&cellcur[3 * NC + t * N_NODES + src], 1) - (2 * E1 + E2);
        bucketS2[ps] = e;
    }
}

// ---------------- f32 -> bf16 elementwise convert (x and W) ----------------

__global__ __launch_bounds__(256) void k_cvt(const float* __restrict__ in,
        unsigned short* __restrict__ ob, int n8) {
    int i = blockIdx.x * 256 + threadIdx.x;
    if (i >= n8) return;
    const float4* p = (const float4*)in + (size_t)i * 2;
    float4 v0 = p[0], v1 = p[1];
    union { unsigned short us[8]; uint4 u4; } o;
    o.us[0] = f2bf(v0.x); o.us[1] = f2bf(v0.y); o.us[2] = f2bf(v0.z); o.us[3] = f2bf(v0.w);
    o.us[4] = f2bf(v1.x); o.us[5] = f2bf(v1.y); o.us[6] = f2bf(v1.z); o.us[7] = f2bf(v1.w);
    *(uint4*)(ob + (size_t)i * 8) = o.u4;
}

// ---------------- A[t][K][D] -> AT[t][D][K] bf16 (transpose + convert) ----------------

__global__ void k_cvt_At(const float* __restrict__ A, unsigned short* __restrict__ AT, int K) {
    __shared__ float tl[32][33];
    const float* Ab = A + (size_t)blockIdx.z * K * D;
    unsigned short* Ob = AT + (size_t)blockIdx.z * D * K;
    int k0 = blockIdx.x * 32, j0 = blockIdx.y * 32;
    int lx = threadIdx.x, ly = threadIdx.y;   // 32 x 8
    for (int yy = ly; yy < 32; yy += 8)
        tl[yy][lx] = Ab[(size_t)(k0 + yy) * D + j0 + lx];
    __syncthreads();
    for (int yy = ly; yy < 32; yy += 8)
        Ob[(size_t)(j0 + yy) * K + k0 + lx] = f2bf(tl[lx][yy]);
}

// ---------------- dense: out = x @ W^T + b  (MFMA bf16) ----------------

__global__ __launch_bounds__(256) void k_init_mfma(const unsigned short* __restrict__ xb,
        const unsigned short* __restrict__ Wb, const float* __restrict__ bias,
        float* __restrict__ out, int n) {
    __shared__ __align__(16) char xs[64 * 128];
    int row0 = blockIdx.x * 64;
    int tid = threadIdx.x;
    int lane = tid & 63, w = tid >> 6;
    int l15 = lane & 15, l4 = lane >> 4;
    f32x4 acc[4][4];
    #pragma unroll
    for (int m = 0; m < 4; ++m)
        #pragma unroll
        for (int nn = 0; nn < 4; ++nn) acc[m][nn] = (f32x4)0.f;

    for (int kk = 0; kk < D; kk += 64) {
        #pragma unroll
        for (int it = 0; it < 2; ++it) {
            int f = it * 256 + tid;
            int r = f >> 3, q0 = f & 7;
            int q = q0 ^ (r & 7);
            int gr = row0 + r; if (gr >= n) gr = n - 1;
            gload_lds16(xb + (size_t)gr * D + kk + q * 8, xs + f * 16);
        }
        bf16x8 bfr[2][4];
        #pragma unroll
        for (int ks = 0; ks < 2; ++ks)
            #pragma unroll
            for (int nn = 0; nn < 4; ++nn) {
                int j = w * 64 + nn * 16 + l15;
                int k = kk + ks * 32 + l4 * 8;
                bfr[ks][nn] = *(const bf16x8*)(Wb + (size_t)j * D + k);
            }
        __syncthreads();
        #pragma unroll
        for (int ks = 0; ks < 2; ++ks)
            #pragma unroll
            for (int m = 0; m < 4; ++m) {
                int R = m * 16 + l15;
                int C = ks * 4 + l4;
                bf16x8 a = *(const bf16x8*)(xs + R * 128 + ((C ^ (R & 7)) << 4));
                #pragma unroll
                for (int nn = 0; nn < 4; ++nn)
                    acc[m][nn] = __builtin_amdgcn_mfma_f32_16x16x32_bf16(
                        a, bfr[ks][nn], acc[m][nn], 0, 0, 0);
            }
        __syncthreads();
    }
    #pragma unroll
    for (int m = 0; m < 4; ++m)
        #pragma unroll
        for (int nn = 0; nn < 4; ++nn) {
            int col = w * 64 + nn * 16 + l15;
            float bv = bias[col];
            #pragma unroll
            for (int r = 0; r < 4; ++r) {
                int row = row0 + m * 16 + l4 * 4 + r;
                if (row < n) out[(size_t)row * D + col] = acc[m][nn][r] + bv;
            }
        }
}

// ---------------- per-type gather-GEMM over SRC-SORTED tiles ----------------
// Tiles walk the (t,src0)-sorted bucket -> gathers sweep xb nearly sequentially
// (L2/L3-local). Each finished row is scattered to eo at the edge's dst-rank
// (epos) -- full 512B line writes, no RMW. Reduce layout unchanged.

template<int SHAPE, int SCR>
__global__ __launch_bounds__(256, 4) void k_edge_mfma(const unsigned short* __restrict__ xb,
        const int* __restrict__ idx, const unsigned short* __restrict__ AT,
        float* __restrict__ out, unsigned short* __restrict__ eo, int E,
        const int* __restrict__ countsD, const int* __restrict__ cellofsS, int rebaseS,
        const int* __restrict__ bucketS, const int* __restrict__ epos) {
    constexpr int K = SHAPE * 256;
    __shared__ __align__(16) unsigned short re[16][264];   // epilogue repack only
    __shared__ __align__(16) char xs[64 * 128];
    __shared__ int srcS[SHAPE][64];
    __shared__ int dstS[64];
    __shared__ int eposS[64];
    __shared__ float normS[64];

    int t = blockIdx.y;
    int offs_t = cellofsS[t * N_NODES] - rebaseS;
    int end_t = (t == NT - 1) ? E : cellofsS[(t + 1) * N_NODES] - rebaseS;
    int cnt = end_t - offs_t;
    int tile = blockIdx.x * 64;
    if (tile >= cnt) return;
    int nE = min(64, cnt - tile);
    int base = offs_t + tile;
    int tid = threadIdx.x;

    if (tid < 64) {
        bool valid = tid < nE;
        int e = bucketS[base + (valid ? tid : 0)];
        int dst = idx[(size_t)SHAPE * E + (size_t)SHAPE * e];
        dstS[tid] = dst;
        eposS[tid] = epos[e];
        int c = countsD[t * N_NODES + dst];
        normS[tid] = valid ? 1.0f / (float)(c > 1 ? c : 1) : 0.0f;
        srcS[0][tid] = idx[SHAPE * e];
        if (SHAPE == 2) srcS[SHAPE - 1][tid] = idx[SHAPE * e + SHAPE - 1];
    }
    __syncthreads();

    const unsigned short* Bt = AT + (size_t)t * D * K;
    int lane = tid & 63, w = tid >> 6;
    int l15 = lane & 15, l4 = lane >> 4;
    f32x4 acc[4][4];
    #pragma unroll
    for (int m = 0; m < 4; ++m)
        #pragma unroll
        for (int nn = 0; nn < 4; ++nn) acc[m][nn] = (f32x4)0.f;

    for (int kk = 0; kk < K; kk += 64) {
        #pragma unroll
        for (int it = 0; it < 2; ++it) {
            int f = it * 256 + tid;
            int r = f >> 3, q0 = f & 7;
            int q = q0 ^ (r & 7);
            int node = srcS[SHAPE == 2 ? (kk >> 8) : 0][r];
            int col = (kk & 255) + q * 8;
            gload_lds16(xb + (size_t)node * D + col, xs + f * 16);
        }
        bf16x8 bfr[2][4];
        #pragma unroll
        for (int ks = 0; ks < 2; ++ks)
            #pragma unroll
            for (int nn = 0; nn < 4; ++nn) {
                int j = w * 64 + nn * 16 + l15;
                int k = kk + ks * 32 + l4 * 8;
                bfr[ks][nn] = *(const bf16x8*)(Bt + (size_t)j * K + k);
            }
        __syncthreads();
        #pragma unroll
        for (int ks = 0; ks < 2; ++ks)
            #pragma unroll
            for (int m = 0; m < 4; ++m) {
                int R = m * 16 + l15;
                int C = ks * 4 + l4;
                bf16x8 a = *(const bf16x8*)(xs + R * 128 + ((C ^ (R & 7)) << 4));
                #pragma unroll
                for (int nn = 0; nn < 4; ++nn)
                    acc[m][nn] = __builtin_amdgcn_mfma_f32_16x16x32_bf16(
                        a, bfr[ks][nn], acc[m][nn], 0, 0, 0);
            }
        __syncthreads();
    }

    if constexpr (SCR) {
        #pragma unroll
        for (int q = 0; q < 4; ++q) {          // quarter q handles rows q*16..q*16+15
            __syncthreads();
            #pragma unroll
            for (int r = 0; r < 4; ++r) {
                int rl = l4 * 4 + r;
                float nm = normS[q * 16 + rl];
                #pragma unroll
                for (int nn = 0; nn < 4; ++nn) {
                    int col = w * 64 + nn * 16 + l15;
                    re[rl][col] = f2bf(nm * acc[q][nn][r]);
                }
            }
            __syncthreads();
            #pragma unroll
            for (int it = 0; it < 2; ++it) {
                int f = it * 256 + tid;
                int row = f >> 5, seg = f & 31;
                int grow = q * 16 + row;
                if (grow < nE) {
                    uint32x4 v = *(const uint32x4*)&re[row][seg * 8];
                    *(uint32x4*)(eo + (size_t)eposS[grow] * D + seg * 8) = v;
                }
            }
        }
    } else {
        #pragma unroll
        for (int m = 0; m < 4; ++m)
            #pragma unroll
            for (int r = 0; r < 4; ++r) {
                int rr = m * 16 + l4 * 4 + r;
                if (rr < nE) {
                    float nm = normS[rr];
                    size_t ob = (size_t)dstS[rr] * D;
                    #pragma unroll
                    for (int nn = 0; nn < 4; ++nn) {
                        int col = w * 64 + nn * 16 + l15;
                        atomicAdd(&out[ob + col], nm * acc[m][nn][r]);
                    }
                }
            }
    }
}

// ---------------- dst-owned reduction: out[dst] += sum of scratch runs ----------------

__device__ __forceinline__ void acc_runs(const unsigned short* __restrict__ eo,
        const int* __restrict__ counts, const int* __restrict__ cellofs, int rebase,
        int dst, int lane, float& a0, float& a1, float& a2, float& a3, int& tot) {
    #pragma unroll
    for (int t = 0; t < NT; ++t) {
        int start = cellofs[t * N_NODES + dst] - rebase;
        int c = counts[t * N_NODES + dst];
        tot += c;
        for (int i = 0; i < c; ++i) {
            const uint32x2* row = (const uint32x2*)(eo + (size_t)(start + i) * D + lane * 4);
            uint32x2 v = __builtin_nontemporal_load(row);
            a0 += __uint_as_float(v.x << 16);
            a1 += __uint_as_float(v.x & 0xFFFF0000u);
            a2 += __uint_as_float(v.y << 16);
            a3 += __uint_as_float(v.y & 0xFFFF0000u);
        }
    }
}

__global__ __launch_bounds__(256) void k_reduce_two(
        const unsigned short* __restrict__ eo1, const int* __restrict__ c1,
        const int* __restrict__ o1,
        const unsigned short* __restrict__ eo2, const int* __restrict__ c2,
        const int* __restrict__ o2, int rb2,
        float* __restrict__ out) {
    int wv = threadIdx.x >> 6, lane = threadIdx.x & 63;
    int dst = blockIdx.x * 4 + wv;
    if (dst >= N_NODES) return;
    float a0 = 0.f, a1 = 0.f, a2 = 0.f, a3 = 0.f;
    int tot = 0;
    acc_runs(eo1, c1, o1, 0, dst, lane, a0, a1, a2, a3, tot);
    acc_runs(eo2, c2, o2, rb2, dst, lane, a0, a1, a2, a3, tot);
    if (tot) {
        float4* o = (float4*)&out[(size_t)dst * D + lane * 4];
        float4 cur = *o;
        cur.x += a0; cur.y += a1; cur.z += a2; cur.w += a3;
        *o = cur;
    }
}

// ---------------- launch ----------------

extern "C" void kernel_launch(void* const* d_in, const int* in_sizes, int n_in,
                              void* d_out, int out_size, void* d_ws, size_t ws_size,
                              hipStream_t stream) {
    const float* x  = (const float*)d_in[0];
    const int* idx1 = (const int*)d_in[1];
    const int* ty1  = (const int*)d_in[2];
    const int* idx2 = (const int*)d_in[3];
    const int* ty2  = (const int*)d_in[4];
    const float* A1 = (const float*)d_in[5];
    const float* A2 = (const float*)d_in[6];
    const float* W  = (const float*)d_in[7];
    const float* b  = (const float*)d_in[8];
    float* out = (float*)d_out;

    int E1 = in_sizes[2];
    int E2 = in_sizes[4];
    int maxE = E1 > E2 ? E1 : E2;
    const int NCELL = NT * N_NODES;
    const int NC4 = 4 * NCELL;
    const int NB4 = (NC4 + 1023) / 1024;
    const int NRB = (N_NODES + 3) / 4;

    char* p = (char*)d_ws;
    unsigned short* xb  = (unsigned short*)p; p += (size_t)N_NODES * D * 2;   // 51.2 MB
    unsigned short* Wb  = (unsigned short*)p; p += (size_t)D * D * 2;
    unsigned short* A1T = (unsigned short*)p; p += (size_t)NT * D * 256 * 2;
    unsigned short* A2T = (unsigned short*)p; p += (size_t)NT * D * 512 * 2;
    int* counts  = (int*)p; p += (size_t)NC4 * 4;     // dst1|dst2|src1|src2
    int* cellofs = (int*)p; p += (size_t)NC4 * 4;
    int* cellcur = (int*)p; p += (size_t)NC4 * 4;
    int* bsums   = (int*)p; p += 2048 * 4;
    int* epos1   = (int*)p; p += (size_t)maxE * 4;
    int* epos2   = (int*)p; p += (size_t)maxE * 4;
    int* bucketS1= (int*)p; p += (size_t)maxE * 4;
    int* bucketS2= (int*)p; p += (size_t)maxE * 4;
    unsigned short* eo1 = (unsigned short*)p; p += (size_t)maxE * D * 2;      // 153.6 MB
    unsigned short* eo2 = (unsigned short*)p; p += (size_t)maxE * D * 2;      // 153.6 MB
    size_t need2 = (size_t)(p - (char*)d_ws);
    int mode = (need2 <= ws_size) ? 2 : 0;
    int* countsD2  = counts + NCELL;
    int* cellofsD2 = cellofs + NCELL;
    const int rbS1 = E1 + E2;
    const int rbS2 = 2 * E1 + E2;

    // ---- prep: bf16 conversions / transposes ----
    k_cvt<<<(N_NODES * D / 8 + 255) / 256, 256, 0, stream>>>(x, xb, N_NODES * D / 8);
    k_cvt<<<(D * D / 8 + 255) / 256, 256, 0, stream>>>(W, Wb, D * D / 8);
    k_cvt_At<<<dim3(256 / 32, D / 32, NT), dim3(32, 8), 0, stream>>>(A1, A1T, 256);
    k_cvt_At<<<dim3(512 / 32, D / 32, NT), dim3(32, 8), 0, stream>>>(A2, A2T, 512);

    // ---- dense part ----
    k_init_mfma<<<(N_NODES + 63) / 64, 256, 0, stream>>>(xb, Wb, b, out, N_NODES);

    // ---- fused prep: count(dst+src) -> joint scan -> place(epos + src bucket) ----
    hipMemsetAsync(counts, 0, (size_t)NC4 * sizeof(int), stream);
    k_count_all<<<(maxE + 255) / 256, 256, 0, stream>>>(idx1, ty1, E1, idx2, ty2, E2, counts);
    k_scan1<<<NB4, 256, 0, stream>>>(counts, NC4, cellofs, bsums);
    k_scan2<<<1, 1024, 0, stream>>>(bsums, NB4);
    k_scan3<<<NB4, 256, 0, stream>>>(cellofs, cellcur, bsums, NC4);
    k_place_all<<<(maxE + 255) / 256, 256, 0, stream>>>(idx1, ty1, E1, epos1, bucketS1,
                                                        idx2, ty2, E2, epos2, bucketS2, cellcur);

    // ---- edge GEMMs (src-sorted) + fused reduce ----
    if (mode == 2) {
        k_edge_mfma<1, 1><<<dim3((E1 + 63) / 64, NT), 256, 0, stream>>>(
            xb, idx1, A1T, out, eo1, E1,
            counts, cellofs + 2 * NCELL, rbS1, bucketS1, epos1);
        k_edge_mfma<2, 1><<<dim3((E2 + 63) / 64, NT), 256, 0, stream>>>(
            xb, idx2, A2T, out, eo2, E2,
            countsD2, cellofs + 3 * NCELL, rbS2, bucketS2, epos2);
        k_reduce_two<<<NRB, 256, 0, stream>>>(eo1, counts, cellofs,
                                              eo2, countsD2, cellofsD2, E1, out);
    } else {
        k_edge_mfma<1, 0><<<dim3((E1 + 63) / 64, NT), 256, 0, stream>>>(
            xb, idx1, A1T, out, nullptr, E1,
            counts, cellofs + 2 * NCELL, rbS1, bucketS1, epos1);
        k_edge_mfma<2, 0><<<dim3((E2 + 63) / 64, NT), 256, 0, stream>>>(
            xb, idx2, A2T, out, nullptr, E2,
            countsD2, cellofs + 3 * NCELL, rbS2, bucketS2, epos2);
    }
}

// Round 14
// 573.614 us; speedup vs baseline: 1.1088x; 1.1088x over previous
//
#include <hip/hip_runtime.h>
#include <stdint.h>

#define N_NODES 100000
#define D 256
#define NT 4

typedef float f32x4 __attribute__((ext_vector_type(4)));
typedef __bf16 bf16x8 __attribute__((ext_vector_type(8)));
typedef unsigned int uint32x4 __attribute__((ext_vector_type(4)));
typedef unsigned int uint32x2 __attribute__((ext_vector_type(2)));

__device__ __forceinline__ unsigned short f2bf(float f) {
    unsigned u = __float_as_uint(f);
    u += 0x7FFF + ((u >> 16) & 1);        // round-to-nearest-even
    return (unsigned short)(u >> 16);
}

__device__ __forceinline__ void gload_lds16(const void* g, void* lds) {
    __builtin_amdgcn_global_load_lds(
        (const __attribute__((address_space(1))) unsigned int*)g,
        (__attribute__((address_space(3))) unsigned int*)lds, 16, 0, 0);
}

// ---------------- fused per-(type,dst) counting for BOTH stages ----------------

__global__ void k_count_both(const int* __restrict__ idx1, const int* __restrict__ ty1, int E1,
                             const int* __restrict__ idx2, const int* __restrict__ ty2, int E2,
                             int* __restrict__ counts) {
    int e = blockIdx.x * 256 + threadIdx.x;
    if (e < E1) {
        int t = ty1[e];
        int dst = idx1[(size_t)E1 + e];
        atomicAdd(&counts[t * N_NODES + dst], 1);
    }
    if (e < E2) {
        int t = ty2[e];
        int dst = idx2[(size_t)2 * E2 + (size_t)2 * e];
        atomicAdd(&counts[NT * N_NODES + t * N_NODES + dst], 1);
    }
}

// ---------------- exclusive scan over 2*NT*N_NODES cells (3 kernels) ----------------

__global__ __launch_bounds__(256) void k_scan1(const int* __restrict__ in, int n,
        int* __restrict__ outv, int* __restrict__ bsums) {
    __shared__ int s[256];
    int tid = threadIdx.x;
    int i = blockIdx.x * 1024 + tid * 4;
    int v0 = 0, v1 = 0, v2 = 0, v3 = 0;
    if (i + 3 < n) {
        int4 v = *(const int4*)(in + i);
        v0 = v.x; v1 = v.y; v2 = v.z; v3 = v.w;
    } else {
        if (i     < n) v0 = in[i];
        if (i + 1 < n) v1 = in[i + 1];
        if (i + 2 < n) v2 = in[i + 2];
        if (i + 3 < n) v3 = in[i + 3];
    }
    int tsum = v0 + v1 + v2 + v3;
    s[tid] = tsum; __syncthreads();
    for (int off = 1; off < 256; off <<= 1) {
        int t = (tid >= off) ? s[tid - off] : 0;
        __syncthreads();
        s[tid] += t;
        __syncthreads();
    }
    int excl = s[tid] - tsum;
    if (tid == 255) bsums[blockIdx.x] = s[255];
    int o0 = excl, o1 = o0 + v0, o2 = o1 + v1, o3 = o2 + v2;
    if (i + 3 < n) {
        *(int4*)(outv + i) = make_int4(o0, o1, o2, o3);
    } else {
        if (i     < n) outv[i]     = o0;
        if (i + 1 < n) outv[i + 1] = o1;
        if (i + 2 < n) outv[i + 2] = o2;
        if (i + 3 < n) outv[i + 3] = o3;
    }
}

__global__ __launch_bounds__(1024) void k_scan2(int* __restrict__ bsums, int nb) {
    __shared__ int s[1024];
    int t = threadIdx.x;
    int v = (t < nb) ? bsums[t] : 0;
    s[t] = v; __syncthreads();
    for (int off = 1; off < 1024; off <<= 1) {
        int u = (t >= off) ? s[t - off] : 0;
        __syncthreads();
        s[t] += u;
        __syncthreads();
    }
    if (t < nb) bsums[t] = s[t] - v;   // exclusive
}

__global__ __launch_bounds__(256) void k_scan3(int* __restrict__ cellofs,
        int* __restrict__ cellcur, const int* __restrict__ bsums, int n) {
    int i = blockIdx.x * 1024 + threadIdx.x * 4;
    int add = bsums[blockIdx.x];
    if (i + 3 < n) {
        int4 v = *(int4*)(cellofs + i);
        v.x += add; v.y += add; v.z += add; v.w += add;
        *(int4*)(cellofs + i) = v;
        *(int4*)(cellcur + i) = v;
    } else {
        for (int k = 0; k < 4; ++k)
            if (i + k < n) { int v = cellofs[i + k] + add; cellofs[i + k] = v; cellcur[i + k] = v; }
    }
}

// ---------------- fused (type,dst)-sorted placement for BOTH stages ----------------
// stage-2 scan values are offset by E1 (joint scan) -> rebase positions by E1.

__global__ void k_place_both(const int* __restrict__ idx1, const int* __restrict__ ty1, int E1,
                             int* __restrict__ bucket1,
                             const int* __restrict__ idx2, const int* __restrict__ ty2, int E2,
                             int* __restrict__ bucket2,
                             int* __restrict__ cellcur) {
    int e = blockIdx.x * 256 + threadIdx.x;
    if (e < E1) {
        int t = ty1[e];
        int dst = idx1[(size_t)E1 + e];
        int pos = atomicAdd(&cellcur[t * N_NODES + dst], 1);
        bucket1[pos] = e;
    }
    if (e < E2) {
        int t = ty2[e];
        int dst = idx2[(size_t)2 * E2 + (size_t)2 * e];
        int pos = atomicAdd(&cellcur[NT * N_NODES + t * N_NODES + dst], 1) - E1;
        bucket2[pos] = e;
    }
}

// ---------------- f32 -> bf16 elementwise convert (x and W) ----------------

__global__ __launch_bounds__(256) void k_cvt(const float* __restrict__ in,
        unsigned short* __restrict__ ob, int n8) {
    int i = blockIdx.x * 256 + threadIdx.x;
    if (i >= n8) return;
    const float4* p = (const float4*)in + (size_t)i * 2;
    float4 v0 = p[0], v1 = p[1];
    union { unsigned short us[8]; uint4 u4; } o;
    o.us[0] = f2bf(v0.x); o.us[1] = f2bf(v0.y); o.us[2] = f2bf(v0.z); o.us[3] = f2bf(v0.w);
    o.us[4] = f2bf(v1.x); o.us[5] = f2bf(v1.y); o.us[6] = f2bf(v1.z); o.us[7] = f2bf(v1.w);
    *(uint4*)(ob + (size_t)i * 8) = o.u4;
}

// ---------------- A[t][K][D] -> AT[t][D][K] bf16 (transpose + convert) ----------------

__global__ void k_cvt_At(const float* __restrict__ A, unsigned short* __restrict__ AT, int K) {
    __shared__ float tl[32][33];
    const float* Ab = A + (size_t)blockIdx.z * K * D;
    unsigned short* Ob = AT + (size_t)blockIdx.z * D * K;
    int k0 = blockIdx.x * 32, j0 = blockIdx.y * 32;
    int lx = threadIdx.x, ly = threadIdx.y;   // 32 x 8
    for (int yy = ly; yy < 32; yy += 8)
        tl[yy][lx] = Ab[(size_t)(k0 + yy) * D + j0 + lx];
    __syncthreads();
    for (int yy = ly; yy < 32; yy += 8)
        Ob[(size_t)(j0 + yy) * K + k0 + lx] = f2bf(tl[lx][yy]);
}

// ---------------- dense: out = x @ W^T + b  (MFMA bf16) ----------------

__global__ __launch_bounds__(256) void k_init_mfma(const unsigned short* __restrict__ xb,
        const unsigned short* __restrict__ Wb, const float* __restrict__ bias,
        float* __restrict__ out, int n) {
    __shared__ __align__(16) char xs[64 * 128];
    int row0 = blockIdx.x * 64;
    int tid = threadIdx.x;
    int lane = tid & 63, w = tid >> 6;
    int l15 = lane & 15, l4 = lane >> 4;
    f32x4 acc[4][4];
    #pragma unroll
    for (int m = 0; m < 4; ++m)
        #pragma unroll
        for (int nn = 0; nn < 4; ++nn) acc[m][nn] = (f32x4)0.f;

    for (int kk = 0; kk < D; kk += 64) {
        #pragma unroll
        for (int it = 0; it < 2; ++it) {
            int f = it * 256 + tid;
            int r = f >> 3, q0 = f & 7;
            int q = q0 ^ (r & 7);
            int gr = row0 + r; if (gr >= n) gr = n - 1;
            gload_lds16(xb + (size_t)gr * D + kk + q * 8, xs + f * 16);
        }
        bf16x8 bfr[2][4];
        #pragma unroll
        for (int ks = 0; ks < 2; ++ks)
            #pragma unroll
            for (int nn = 0; nn < 4; ++nn) {
                int j = w * 64 + nn * 16 + l15;
                int k = kk + ks * 32 + l4 * 8;
                bfr[ks][nn] = *(const bf16x8*)(Wb + (size_t)j * D + k);
            }
        __syncthreads();
        #pragma unroll
        for (int ks = 0; ks < 2; ++ks)
            #pragma unroll
            for (int m = 0; m < 4; ++m) {
                int R = m * 16 + l15;
                int C = ks * 4 + l4;
                bf16x8 a = *(const bf16x8*)(xs + R * 128 + ((C ^ (R & 7)) << 4));
                #pragma unroll
                for (int nn = 0; nn < 4; ++nn)
                    acc[m][nn] = __builtin_amdgcn_mfma_f32_16x16x32_bf16(
                        a, bfr[ks][nn], acc[m][nn], 0, 0, 0);
            }
        __syncthreads();
    }
    #pragma unroll
    for (int m = 0; m < 4; ++m)
        #pragma unroll
        for (int nn = 0; nn < 4; ++nn) {
            int col = w * 64 + nn * 16 + l15;
            float bv = bias[col];
            #pragma unroll
            for (int r = 0; r < 4; ++r) {
                int row = row0 + m * 16 + l4 * 4 + r;
                if (row < n) out[(size_t)row * D + col] = acc[m][nn][r] + bv;
            }
        }
}

// ---------------- per-type gather-GEMM (r9 structure) + scratch/atomic epilogue ----------------
// rebase: stage-2 joint-scan offsets are shifted by E1; positions into
// bucket/eo are (cellofs - rebase).

template<int SHAPE, int SCR>
__global__ __launch_bounds__(256, 4) void k_edge_mfma(const unsigned short* __restrict__ xb,
        const int* __restrict__ idx, const unsigned short* __restrict__ AT,
        float* __restrict__ out, unsigned short* __restrict__ eo, int E, int rebase,
        const int* __restrict__ counts, const int* __restrict__ cellofs,
        const int* __restrict__ bucket) {
    constexpr int K = SHAPE * 256;
    __shared__ __align__(16) unsigned short re[16][264];   // epilogue repack only
    __shared__ __align__(16) char xs[64 * 128];
    __shared__ int srcS[SHAPE][64];
    __shared__ int dstS[64];
    __shared__ float normS[64];

    int t = blockIdx.y;
    int offs_t = cellofs[t * N_NODES] - rebase;
    int end_t = (t == NT - 1) ? E : cellofs[(t + 1) * N_NODES] - rebase;
    int cnt = end_t - offs_t;
    int tile = blockIdx.x * 64;
    if (tile >= cnt) return;
    int nE = min(64, cnt - tile);
    int base = offs_t + tile;
    int tid = threadIdx.x;

    if (tid < 64) {
        bool valid = tid < nE;
        int e = bucket[base + (valid ? tid : 0)];
        int dst = idx[(size_t)SHAPE * E + (size_t)SHAPE * e];
        dstS[tid] = dst;
        int c = counts[t * N_NODES + dst];
        normS[tid] = valid ? 1.0f / (float)(c > 1 ? c : 1) : 0.0f;
        srcS[0][tid] = idx[SHAPE * e];
        if (SHAPE == 2) srcS[SHAPE - 1][tid] = idx[SHAPE * e + SHAPE - 1];
    }
    __syncthreads();

    const unsigned short* Bt = AT + (size_t)t * D * K;
    int lane = tid & 63, w = tid >> 6;
    int l15 = lane & 15, l4 = lane >> 4;
    f32x4 acc[4][4];
    #pragma unroll
    for (int m = 0; m < 4; ++m)
        #pragma unroll
        for (int nn = 0; nn < 4; ++nn) acc[m][nn] = (f32x4)0.f;

    for (int kk = 0; kk < K; kk += 64) {
        #pragma unroll
        for (int it = 0; it < 2; ++it) {
            int f = it * 256 + tid;
            int r = f >> 3, q0 = f & 7;
            int q = q0 ^ (r & 7);
            int node = srcS[SHAPE == 2 ? (kk >> 8) : 0][r];
            int col = (kk & 255) + q * 8;
            gload_lds16(xb + (size_t)node * D + col, xs + f * 16);
        }
        bf16x8 bfr[2][4];
        #pragma unroll
        for (int ks = 0; ks < 2; ++ks)
            #pragma unroll
            for (int nn = 0; nn < 4; ++nn) {
                int j = w * 64 + nn * 16 + l15;
                int k = kk + ks * 32 + l4 * 8;
                bfr[ks][nn] = *(const bf16x8*)(Bt + (size_t)j * K + k);
            }
        __syncthreads();
        #pragma unroll
        for (int ks = 0; ks < 2; ++ks)
            #pragma unroll
            for (int m = 0; m < 4; ++m) {
                int R = m * 16 + l15;
                int C = ks * 4 + l4;
                bf16x8 a = *(const bf16x8*)(xs + R * 128 + ((C ^ (R & 7)) << 4));
                #pragma unroll
                for (int nn = 0; nn < 4; ++nn)
                    acc[m][nn] = __builtin_amdgcn_mfma_f32_16x16x32_bf16(
                        a, bfr[ks][nn], acc[m][nn], 0, 0, 0);
            }
        __syncthreads();
    }

    if constexpr (SCR) {
        #pragma unroll
        for (int q = 0; q < 4; ++q) {          // quarter q handles rows q*16..q*16+15
            __syncthreads();
            #pragma unroll
            for (int r = 0; r < 4; ++r) {
                int rl = l4 * 4 + r;
                float nm = normS[q * 16 + rl];
                #pragma unroll
                for (int nn = 0; nn < 4; ++nn) {
                    int col = w * 64 + nn * 16 + l15;
                    re[rl][col] = f2bf(nm * acc[q][nn][r]);
                }
            }
            __syncthreads();
            #pragma unroll
            for (int it = 0; it < 2; ++it) {
                int f = it * 256 + tid;
                int row = f >> 5, seg = f & 31;
                int grow = q * 16 + row;
                if (grow < nE) {
                    uint32x4 v = *(const uint32x4*)&re[row][seg * 8];
                    *(uint32x4*)(eo + (size_t)(base + grow) * D + seg * 8) = v;
                }
            }
        }
    } else {
        #pragma unroll
        for (int m = 0; m < 4; ++m)
            #pragma unroll
            for (int r = 0; r < 4; ++r) {
                int rr = m * 16 + l4 * 4 + r;
                if (rr < nE) {
                    float nm = normS[rr];
                    size_t ob = (size_t)dstS[rr] * D;
                    #pragma unroll
                    for (int nn = 0; nn < 4; ++nn) {
                        int col = w * 64 + nn * 16 + l15;
                        atomicAdd(&out[ob + col], nm * acc[m][nn][r]);
                    }
                }
            }
    }
}

// ---------------- dst-owned reduction(s): out[dst] += sum of scratch runs ----------------

__device__ __forceinline__ void acc_runs(const unsigned short* __restrict__ eo,
        const int* __restrict__ counts, const int* __restrict__ cellofs, int rebase,
        int dst, int lane, float& a0, float& a1, float& a2, float& a3, int& tot) {
    #pragma unroll
    for (int t = 0; t < NT; ++t) {
        int start = cellofs[t * N_NODES + dst] - rebase;
        int c = counts[t * N_NODES + dst];
        tot += c;
        for (int i = 0; i < c; ++i) {
            const uint32x2* row = (const uint32x2*)(eo + (size_t)(start + i) * D + lane * 4);
            uint32x2 v = __builtin_nontemporal_load(row);
            a0 += __uint_as_float(v.x << 16);
            a1 += __uint_as_float(v.x & 0xFFFF0000u);
            a2 += __uint_as_float(v.y << 16);
            a3 += __uint_as_float(v.y & 0xFFFF0000u);
        }
    }
}

__global__ __launch_bounds__(256) void k_reduce_two(
        const unsigned short* __restrict__ eo1, const int* __restrict__ c1,
        const int* __restrict__ o1,
        const unsigned short* __restrict__ eo2, const int* __restrict__ c2,
        const int* __restrict__ o2, int rb2,
        float* __restrict__ out) {
    int wv = threadIdx.x >> 6, lane = threadIdx.x & 63;
    int dst = blockIdx.x * 4 + wv;
    if (dst >= N_NODES) return;
    float a0 = 0.f, a1 = 0.f, a2 = 0.f, a3 = 0.f;
    int tot = 0;
    acc_runs(eo1, c1, o1, 0, dst, lane, a0, a1, a2, a3, tot);
    acc_runs(eo2, c2, o2, rb2, dst, lane, a0, a1, a2, a3, tot);
    if (tot) {
        float4* o = (float4*)&out[(size_t)dst * D + lane * 4];
        float4 cur = *o;
        cur.x += a0; cur.y += a1; cur.z += a2; cur.w += a3;
        *o = cur;
    }
}

// ---------------- launch ----------------

extern "C" void kernel_launch(void* const* d_in, const int* in_sizes, int n_in,
                              void* d_out, int out_size, void* d_ws, size_t ws_size,
                              hipStream_t stream) {
    const float* x  = (const float*)d_in[0];
    const int* idx1 = (const int*)d_in[1];
    const int* ty1  = (const int*)d_in[2];
    const int* idx2 = (const int*)d_in[3];
    const int* ty2  = (const int*)d_in[4];
    const float* A1 = (const float*)d_in[5];
    const float* A2 = (const float*)d_in[6];
    const float* W  = (const float*)d_in[7];
    const float* b  = (const float*)d_in[8];
    float* out = (float*)d_out;

    int E1 = in_sizes[2];
    int E2 = in_sizes[4];
    int maxE = E1 > E2 ? E1 : E2;
    const int NCELL = NT * N_NODES;
    const int NC2 = 2 * NCELL;
    const int NB2 = (NC2 + 1023) / 1024;
    const int NRB = (N_NODES + 3) / 4;

    char* p = (char*)d_ws;
    unsigned short* xb  = (unsigned short*)p; p += (size_t)N_NODES * D * 2;   // 51.2 MB
    unsigned short* Wb  = (unsigned short*)p; p += (size_t)D * D * 2;
    unsigned short* A1T = (unsigned short*)p; p += (size_t)NT * D * 256 * 2;
    unsigned short* A2T = (unsigned short*)p; p += (size_t)NT * D * 512 * 2;
    int* counts  = (int*)p; p += (size_t)NC2 * 4;     // counts1 | counts2
    int* cellofs = (int*)p; p += (size_t)NC2 * 4;     // cellofs1 | cellofs2
    int* cellcur = (int*)p; p += (size_t)NC2 * 4;
    int* bsums   = (int*)p; p += 1024 * 4;
    int* bucket1 = (int*)p; p += (size_t)maxE * 4;
    int* bucket2 = (int*)p; p += (size_t)maxE * 4;
    unsigned short* eo1 = (unsigned short*)p; p += (size_t)maxE * D * 2;      // 153.6 MB
    unsigned short* eo2 = (unsigned short*)p; p += (size_t)maxE * D * 2;      // 153.6 MB
    size_t need2 = (size_t)(p - (char*)d_ws);
    int mode = (need2 <= ws_size) ? 2 : 0;
    int* counts2  = counts + NCELL;
    int* cellofs2 = cellofs + NCELL;

    // ---- prep: bf16 conversions / transposes ----
    k_cvt<<<(N_NODES * D / 8 + 255) / 256, 256, 0, stream>>>(x, xb, N_NODES * D / 8);
    k_cvt<<<(D * D / 8 + 255) / 256, 256, 0, stream>>>(W, Wb, D * D / 8);
    k_cvt_At<<<dim3(256 / 32, D / 32, NT), dim3(32, 8), 0, stream>>>(A1, A1T, 256);
    k_cvt_At<<<dim3(512 / 32, D / 32, NT), dim3(32, 8), 0, stream>>>(A2, A2T, 512);

    // ---- dense part ----
    k_init_mfma<<<(N_NODES + 63) / 64, 256, 0, stream>>>(xb, Wb, b, out, N_NODES);

    // ---- fused prep for both stages: count -> joint scan -> place ----
    hipMemsetAsync(counts, 0, (size_t)NC2 * sizeof(int), stream);
    k_count_both<<<(maxE + 255) / 256, 256, 0, stream>>>(idx1, ty1, E1, idx2, ty2, E2, counts);
    k_scan1<<<NB2, 256, 0, stream>>>(counts, NC2, cellofs, bsums);
    k_scan2<<<1, 1024, 0, stream>>>(bsums, NB2);
    k_scan3<<<NB2, 256, 0, stream>>>(cellofs, cellcur, bsums, NC2);
    k_place_both<<<(maxE + 255) / 256, 256, 0, stream>>>(idx1, ty1, E1, bucket1,
                                                          idx2, ty2, E2, bucket2, cellcur);

    // ---- edge GEMMs + fused reduce ----
    if (mode == 2) {
        k_edge_mfma<1, 1><<<dim3((E1 + 63) / 64, NT), 256, 0, stream>>>(
            xb, idx1, A1T, out, eo1, E1, 0, counts, cellofs, bucket1);
        k_edge_mfma<2, 1><<<dim3((E2 + 63) / 64, NT), 256, 0, stream>>>(
            xb, idx2, A2T, out, eo2, E2, E1, counts2, cellofs2, bucket2);
        k_reduce_two<<<NRB, 256, 0, stream>>>(eo1, counts, cellofs,
                                              eo2, counts2, cellofs2, E1, out);
    } else {
        k_edge_mfma<1, 0><<<dim3((E1 + 63) / 64, NT), 256, 0, stream>>>(
            xb, idx1, A1T, out, nullptr, E1, 0, counts, cellofs, bucket1);
        k_edge_mfma<2, 0><<<dim3((E2 + 63) / 64, NT), 256, 0, stream>>>(
            xb, idx2, A2T, out, nullptr, E2, E1, counts2, cellofs2, bucket2);
    }
}